// Round 1
// baseline (9092.403 us; speedup 1.0000x reference)
//
#include <hip/hip_runtime.h>
#include <hip/hip_bf16.h>
#include <hip/hip_fp16.h>

typedef _Float16 half8 __attribute__((ext_vector_type(8)));
typedef float floatx4 __attribute__((ext_vector_type(4)));

#define INPUT  512
#define HIDDEN 1024
#define OUTPUT 256
#define BATCH  128
#define SEQ    512

// ---------------------------------------------------------------------------
// K0: transpose + fp32->fp16 convert:  in [K][N] f32  ->  out [N][K] f16
// ---------------------------------------------------------------------------
__global__ __launch_bounds__(256) void transpose_f32_to_f16(
    const float* __restrict__ in, _Float16* __restrict__ out, int K, int N) {
  __shared__ float tile[32][33];
  int bi = blockIdx.x;             // K tile
  int bj = blockIdx.y;             // N tile
  int cc = threadIdx.x & 31;
  int rr = threadIdx.x >> 5;       // 0..7
#pragma unroll
  for (int s = 0; s < 4; ++s) {
    int r = rr + 8 * s;
    tile[r][cc] = in[(size_t)(bi * 32 + r) * N + bj * 32 + cc];
  }
  __syncthreads();
#pragma unroll
  for (int s = 0; s < 4; ++s) {
    int nl = rr + 8 * s;
    out[(size_t)(bj * 32 + nl) * K + bi * 32 + cc] = (_Float16)tile[cc][nl];
  }
}

// ---------------------------------------------------------------------------
// K1: xin[M=65536][H=1024] = x[M][512] @ W_in[512][H]   (bias folded later)
// fp16 MFMA 16x16x32, 64x64 tile per block, 4 waves (one 16-row strip each).
// ---------------------------------------------------------------------------
__global__ __launch_bounds__(256) void xin_gemm(
    const float* __restrict__ x, const _Float16* __restrict__ WinT,
    _Float16* __restrict__ xin) {
  int bid = blockIdx.x;
  int bn = bid & 15;               // 16 N-blocks of 64 cols
  int bm = bid >> 4;               // 1024 M-blocks of 64 rows
  int tid = threadIdx.x;
  int l = tid & 63;
  int w = tid >> 6;                // wave 0..3
  int l15 = l & 15;
  int lk = (l >> 4) << 3;          // 0,8,16,24

  int rowbase = bm * 64 + w * 16;
  int colbase = bn * 64;

  floatx4 acc[4];
#pragma unroll
  for (int nt = 0; nt < 4; ++nt) acc[nt] = (floatx4){0.f, 0.f, 0.f, 0.f};

  int arow = rowbase + l15;
  const float* xrow = x + (size_t)arow * INPUT;

  for (int k0 = 0; k0 < INPUT; k0 += 32) {
    int ak = k0 + lk;
    float4 xa = *reinterpret_cast<const float4*>(xrow + ak);
    float4 xb = *reinterpret_cast<const float4*>(xrow + ak + 4);
    half8 a;
    a[0] = (_Float16)xa.x; a[1] = (_Float16)xa.y;
    a[2] = (_Float16)xa.z; a[3] = (_Float16)xa.w;
    a[4] = (_Float16)xb.x; a[5] = (_Float16)xb.y;
    a[6] = (_Float16)xb.z; a[7] = (_Float16)xb.w;
#pragma unroll
    for (int nt = 0; nt < 4; ++nt) {
      int bcol = colbase + nt * 16 + l15;
      half8 b = *reinterpret_cast<const half8*>(WinT + (size_t)bcol * INPUT + ak);
      acc[nt] = __builtin_amdgcn_mfma_f32_16x16x32_f16(a, b, acc[nt], 0, 0, 0);
    }
  }

  int orow = rowbase + ((l >> 4) << 2);   // C/D: row=(l>>4)*4+i, col=l&15
#pragma unroll
  for (int nt = 0; nt < 4; ++nt)
#pragma unroll
    for (int i = 0; i < 4; ++i)
      xin[(size_t)(orow + i) * HIDDEN + colbase + nt * 16 + l15] =
          (_Float16)acc[nt][i];
}

// ---------------------------------------------------------------------------
// K2: persistent weight-stationary recurrence.
// 128 blocks = 8 batch-groups (16 rows) x 16 N-slices (64 cols).
// Block swizzle m=blk&7, j=blk>>3 puts each group's 16 blocks on one XCD
// (round-robin heuristic; correctness is agent-scope atomics regardless).
// 8 waves = 4 ntiles x 2 K-halves; W_h slice lives in B-frag registers.
// ---------------------------------------------------------------------------
__global__ __launch_bounds__(512, 2) void liquid_scan(
    const _Float16* __restrict__ xin,   // [B*S][H]
    const _Float16* __restrict__ WhT,   // [H n][H k] fp16
    const float* __restrict__ b_in, const float* __restrict__ b_h,
    const float* __restrict__ tau,
    _Float16* __restrict__ hbuf,        // [2][B][H] fp16 (buf0 zeroed by memset)
    float* __restrict__ hfinal,         // [B][H] fp32
    int* __restrict__ flags) {          // [128]*16 ints (padded), zeroed
  int blk = blockIdx.x;
  int m = blk & 7;                  // batch group
  int j = blk >> 3;                 // N slice
  int tid = threadIdx.x;
  int l = tid & 63;
  int w = tid >> 6;                 // 0..7
  int nt = w & 3;
  int kg = w >> 2;                  // K half
  int l15 = l & 15;
  int lk = (l >> 4) << 3;

  __shared__ float part[4][64][4];

  // preload W_h slice as B-fragments (16 ktiles of 32)
  int ncol = j * 64 + nt * 16 + l15;
  half8 bfrag[16];
  const _Float16* wbase = WhT + (size_t)ncol * HIDDEN + kg * 512 + lk;
#pragma unroll
  for (int q = 0; q < 16; ++q)
    bfrag[q] = *reinterpret_cast<const half8*>(wbase + q * 32);

  float bias_c = 0.f, invtau_c = 1.f;
  if (kg == 0) {
    bias_c = b_in[ncol] + b_h[ncol];
    invtau_c = 1.0f / tau[ncol];
  }
  float hown[4] = {0.f, 0.f, 0.f, 0.f};

  int hrow = m * 16 + l15;                 // A-frag row (batch index)
  int erow0 = m * 16 + ((l >> 4) << 2);    // epilogue rows base
  int fl = (m * 16 + j) * 16;              // own flag (64B padded)

  for (int t = 0; t < SEQ; ++t) {
    if (t > 0 && tid < 16) {
      const int fi = (m * 16 + tid) * 16;
      while (__hip_atomic_load(&flags[fi], __ATOMIC_ACQUIRE,
                               __HIP_MEMORY_SCOPE_AGENT) < t)
        __builtin_amdgcn_s_sleep(1);
    }
    __syncthreads();  // S1: h_t published by whole group

    float xv[4];
    if (kg == 0) {
#pragma unroll
      for (int i = 0; i < 4; ++i)
        xv[i] = (float)xin[((size_t)(erow0 + i) * SEQ + t) * HIDDEN + ncol];
    }

    const _Float16* habase = hbuf + ((size_t)(t & 1)) * BATCH * HIDDEN +
                             (size_t)hrow * HIDDEN + kg * 512 + lk;
    floatx4 acc = (floatx4){0.f, 0.f, 0.f, 0.f};
#pragma unroll
    for (int q = 0; q < 16; ++q) {
      half8 a = *reinterpret_cast<const half8*>(habase + q * 32);
      acc = __builtin_amdgcn_mfma_f32_16x16x32_f16(a, bfrag[q], acc, 0, 0, 0);
    }

    if (kg == 1) {
#pragma unroll
      for (int i = 0; i < 4; ++i) part[nt][l][i] = acc[i];
    }
    __syncthreads();  // S2: partials ready

    if (kg == 0) {
      _Float16* hw = hbuf + ((size_t)((t + 1) & 1)) * BATCH * HIDDEN;
#pragma unroll
      for (int i = 0; i < 4; ++i) {
        float pre = acc[i] + part[nt][l][i] + xv[i] + bias_c;
        float xc = fminf(fmaxf(pre, -15.f), 15.f);
        float e = __expf(2.f * xc);
        float dx = (e - 1.f) / (e + 1.f);
        float hn = hown[i] + (dx - hown[i]) * invtau_c;
        hown[i] = hn;
        if (t < SEQ - 1)
          hw[(size_t)(erow0 + i) * HIDDEN + ncol] = (_Float16)hn;
        else
          hfinal[(size_t)(erow0 + i) * HIDDEN + ncol] = hn;
      }
      __threadfence();  // make h_{t+1} agent-visible before flag release
    }
    __syncthreads();  // S3: all reads of h_t done + stores fenced

    if (tid == 0 && t < SEQ - 1)
      __hip_atomic_store(&flags[fl], t + 1, __ATOMIC_RELEASE,
                         __HIP_MEMORY_SCOPE_AGENT);
  }
}

// ---------------------------------------------------------------------------
// K3: out[B][256] = hfinal[B][1024] @ W_out + b_out   (fp32, tiny)
// ---------------------------------------------------------------------------
__global__ __launch_bounds__(256) void out_gemm(
    const float* __restrict__ hfinal, const float* __restrict__ Wout,
    const float* __restrict__ bout, float* __restrict__ out) {
  int b0 = blockIdx.x * 2;
  int o = threadIdx.x;
  float a0 = 0.f, a1 = 0.f;
  for (int k = 0; k < HIDDEN; ++k) {
    float wv = Wout[(size_t)k * OUTPUT + o];
    a0 += hfinal[(size_t)b0 * HIDDEN + k] * wv;
    a1 += hfinal[(size_t)(b0 + 1) * HIDDEN + k] * wv;
  }
  out[(size_t)b0 * OUTPUT + o] = a0 + bout[o];
  out[(size_t)(b0 + 1) * OUTPUT + o] = a1 + bout[o];
}

// ---------------------------------------------------------------------------
extern "C" void kernel_launch(void* const* d_in, const int* in_sizes, int n_in,
                              void* d_out, int out_size, void* d_ws,
                              size_t ws_size, hipStream_t stream) {
  const float* x     = (const float*)d_in[0];
  const float* W_in  = (const float*)d_in[1];
  const float* b_in  = (const float*)d_in[2];
  const float* W_h   = (const float*)d_in[3];
  const float* b_h   = (const float*)d_in[4];
  const float* tau   = (const float*)d_in[5];
  const float* W_out = (const float*)d_in[6];
  const float* b_out = (const float*)d_in[7];
  float* out = (float*)d_out;

  char* ws = (char*)d_ws;
  _Float16* xin = (_Float16*)ws;  ws += (size_t)BATCH * SEQ * HIDDEN * 2;  // 134MB
  _Float16* WinT = (_Float16*)ws; ws += (size_t)HIDDEN * INPUT * 2;        // 1MB
  _Float16* WhT = (_Float16*)ws;  ws += (size_t)HIDDEN * HIDDEN * 2;       // 2MB
  _Float16* hbuf = (_Float16*)ws; ws += (size_t)2 * BATCH * HIDDEN * 2;    // 512KB
  float* hfin = (float*)ws;       ws += (size_t)BATCH * HIDDEN * 4;        // 512KB
  int* flags = (int*)ws;          ws += 128 * 16 * 4;                      // 8KB

  // zero the recurrence state (h_0 = 0) and the sync flags
  hipMemsetAsync(hbuf, 0, (size_t)2 * BATCH * HIDDEN * 2, stream);
  hipMemsetAsync(flags, 0, 128 * 16 * 4, stream);

  transpose_f32_to_f16<<<dim3(INPUT / 32, HIDDEN / 32), 256, 0, stream>>>(
      W_in, WinT, INPUT, HIDDEN);
  transpose_f32_to_f16<<<dim3(HIDDEN / 32, HIDDEN / 32), 256, 0, stream>>>(
      W_h, WhT, HIDDEN, HIDDEN);

  xin_gemm<<<(BATCH * SEQ / 64) * (HIDDEN / 64), 256, 0, stream>>>(x, WinT, xin);

  liquid_scan<<<128, 512, 0, stream>>>(xin, WhT, b_in, b_h, tau, hbuf, hfin,
                                       flags);

  out_gemm<<<BATCH / 2, OUTPUT, 0, stream>>>(hfin, W_out, b_out, out);
}

// Round 2
// 3282.067 us; speedup vs baseline: 2.7703x; 2.7703x over previous
//
#include <hip/hip_runtime.h>
#include <hip/hip_fp16.h>

typedef _Float16 half8 __attribute__((ext_vector_type(8)));
typedef float floatx4 __attribute__((ext_vector_type(4)));

#define INPUT  512
#define HIDDEN 1024
#define OUTPUT 256
#define BATCH  128
#define SEQ    512

// ---------------------------------------------------------------------------
// K0: transpose + fp32->fp16 convert:  in [K][N] f32  ->  out [N][K] f16
// ---------------------------------------------------------------------------
__global__ __launch_bounds__(256) void transpose_f32_to_f16(
    const float* __restrict__ in, _Float16* __restrict__ out, int K, int N) {
  __shared__ float tile[32][33];
  int bi = blockIdx.x;             // K tile
  int bj = blockIdx.y;             // N tile
  int cc = threadIdx.x & 31;
  int rr = threadIdx.x >> 5;       // 0..7
#pragma unroll
  for (int s = 0; s < 4; ++s) {
    int r = rr + 8 * s;
    tile[r][cc] = in[(size_t)(bi * 32 + r) * N + bj * 32 + cc];
  }
  __syncthreads();
#pragma unroll
  for (int s = 0; s < 4; ++s) {
    int nl = rr + 8 * s;
    out[(size_t)(bj * 32 + nl) * K + bi * 32 + cc] = (_Float16)tile[cc][nl];
  }
}

// ---------------------------------------------------------------------------
// K1: xin[S][B][H] = x[B*S][512] @ W_in[512][H]  (stored time-major so the
// recurrence reads one contiguous 256KB slab per step)
// ---------------------------------------------------------------------------
__global__ __launch_bounds__(256) void xin_gemm(
    const float* __restrict__ x, const _Float16* __restrict__ WinT,
    _Float16* __restrict__ xin) {
  int bid = blockIdx.x;
  int bn = bid & 15;               // 16 N-blocks of 64 cols
  int bm = bid >> 4;               // 1024 M-blocks of 64 rows
  int tid = threadIdx.x;
  int l = tid & 63;
  int w = tid >> 6;                // wave 0..3
  int l15 = l & 15;
  int lk = (l >> 4) << 3;          // 0,8,16,24

  int rowbase = bm * 64 + w * 16;
  int colbase = bn * 64;

  floatx4 acc[4];
#pragma unroll
  for (int nt = 0; nt < 4; ++nt) acc[nt] = (floatx4){0.f, 0.f, 0.f, 0.f};

  int arow = rowbase + l15;
  const float* xrow = x + (size_t)arow * INPUT;

  for (int k0 = 0; k0 < INPUT; k0 += 32) {
    int ak = k0 + lk;
    float4 xa = *reinterpret_cast<const float4*>(xrow + ak);
    float4 xb = *reinterpret_cast<const float4*>(xrow + ak + 4);
    half8 a;
    a[0] = (_Float16)xa.x; a[1] = (_Float16)xa.y;
    a[2] = (_Float16)xa.z; a[3] = (_Float16)xa.w;
    a[4] = (_Float16)xb.x; a[5] = (_Float16)xb.y;
    a[6] = (_Float16)xb.z; a[7] = (_Float16)xb.w;
#pragma unroll
    for (int nt = 0; nt < 4; ++nt) {
      int bcol = colbase + nt * 16 + l15;
      half8 b = *reinterpret_cast<const half8*>(WinT + (size_t)bcol * INPUT + ak);
      acc[nt] = __builtin_amdgcn_mfma_f32_16x16x32_f16(a, b, acc[nt], 0, 0, 0);
    }
  }

  int orow = rowbase + ((l >> 4) << 2);   // global row = b*512 + s
#pragma unroll
  for (int nt = 0; nt < 4; ++nt)
#pragma unroll
    for (int i = 0; i < 4; ++i) {
      int r = orow + i;
      int b = r >> 9;          // /SEQ
      int s = r & 511;         // %SEQ
      xin[((size_t)s * BATCH + b) * HIDDEN + colbase + nt * 16 + l15] =
          (_Float16)acc[nt][i];
    }
}

// ---------------------------------------------------------------------------
// K2: persistent weight-stationary recurrence with TAGGED-WORD exchange.
// hbuf word = (fp16(h) << 16) | step_tag.  No flags, no fences: consumers
// poll the data itself (relaxed agent-scope = cache-bypassing) until the
// tag matches; producers fire-and-forget relaxed agent-scope stores.
// 128 blocks = 8 batch-groups (16 rows) x 16 N-slices (64 cols).
// All 8 waves cooperatively stage h_t (16x1024) into LDS once per step.
// ---------------------------------------------------------------------------
__global__ __launch_bounds__(512, 1) void liquid_scan(
    const _Float16* __restrict__ xin,   // [S][B][H]
    const _Float16* __restrict__ WhT,   // [H n][H k] fp16
    const float* __restrict__ b_in, const float* __restrict__ b_h,
    const float* __restrict__ tau,
    unsigned int* hbuf,                 // [2][B][H] tagged u32, memset-0
    float* __restrict__ hfinal) {       // [B][H] fp32
  int blk = blockIdx.x;
  int m = blk & 7;                  // batch group
  int j = blk >> 3;                 // N slice
  int tid = threadIdx.x;
  int l = tid & 63;
  int w = tid >> 6;                 // 0..7
  int nt = w & 3;
  int kg = w >> 2;                  // K half
  int l15 = l & 15;
  int lk = (l >> 4) << 3;

  __shared__ _Float16 Ald[16][1032];   // h_t tile, padded (16B-aligned rows)
  __shared__ float part[4][64][4];

  // preload W_h slice as B-fragments (16 ktiles of 32) — stays in VGPRs
  int ncol = j * 64 + nt * 16 + l15;
  half8 bfrag[16];
  const _Float16* wbase = WhT + (size_t)ncol * HIDDEN + kg * 512 + lk;
#pragma unroll
  for (int q = 0; q < 16; ++q)
    bfrag[q] = *reinterpret_cast<const half8*>(wbase + q * 32);

  float bias_c = 0.f, invtau_c = 1.f;
  if (kg == 0) {
    bias_c = b_in[ncol] + b_h[ncol];
    invtau_c = 1.0f / tau[ncol];
  }
  float hown[4] = {0.f, 0.f, 0.f, 0.f};
  int erow0 = m * 16 + ((l >> 4) << 2);    // batch rows this thread owns (kg0)

  // staging: thread tid polls u64 word pairs {row i, cols 2tid..2tid+1}
  unsigned long long* hb64 = (unsigned long long*)hbuf;
  const size_t grp64 = (size_t)(m * 16) * 512;   // group base, u64 units

  for (int t = 0; t < SEQ; ++t) {
    // xin prefetch — independent of h_t, issued before the poll
    float xv[4];
    if (kg == 0) {
#pragma unroll
      for (int i = 0; i < 4; ++i)
        xv[i] = (float)xin[((size_t)t * BATCH + erow0 + i) * HIDDEN + ncol];
    }

    if (t > 0) {
      unsigned long long* bp = hb64 + (size_t)(t & 1) * 65536 + grp64 + tid;
      unsigned long long v[16];
#pragma unroll
      for (int i = 0; i < 16; ++i)
        v[i] = __hip_atomic_load(bp + i * 512, __ATOMIC_RELAXED,
                                 __HIP_MEMORY_SCOPE_AGENT);
      const unsigned long long want =
          (unsigned long long)(unsigned)t | ((unsigned long long)(unsigned)t << 32);
      for (;;) {
        unsigned int bad = 0;
#pragma unroll
        for (int i = 0; i < 16; ++i)
          if (((v[i] ^ want) & 0x0000FFFF0000FFFFull) != 0ull) bad |= 1u << i;
        if (!bad) break;
#pragma unroll
        for (int i = 0; i < 16; ++i)
          if (bad & (1u << i))
            v[i] = __hip_atomic_load(bp + i * 512, __ATOMIC_RELAXED,
                                     __HIP_MEMORY_SCOPE_AGENT);
      }
      // strip tags -> fp16 pair -> LDS (conflict-free: lanes hit distinct banks)
#pragma unroll
      for (int i = 0; i < 16; ++i) {
        unsigned int pk = (unsigned int)((v[i] >> 16) & 0xFFFFu) |
                          ((unsigned int)(v[i] >> 48) << 16);
        *reinterpret_cast<unsigned int*>(&Ald[i][2 * tid]) = pk;
      }
    }
    __syncthreads();   // B1: h_t staged in LDS

    floatx4 acc = (floatx4){0.f, 0.f, 0.f, 0.f};
    if (t > 0) {
      const int kb = kg * 512 + lk;
#pragma unroll
      for (int q = 0; q < 16; ++q) {
        half8 a = *reinterpret_cast<const half8*>(&Ald[l15][kb + q * 32]);
        acc = __builtin_amdgcn_mfma_f32_16x16x32_f16(a, bfrag[q], acc, 0, 0, 0);
      }
    }
    if (kg == 1) {
#pragma unroll
      for (int i = 0; i < 4; ++i) part[nt][l][i] = acc[i];
    }
    __syncthreads();   // B2: partials ready; also protects Ald WAR

    if (kg == 0) {
#pragma unroll
      for (int i = 0; i < 4; ++i) {
        float pre = acc[i] + part[nt][l][i] + xv[i] + bias_c;
        float xc = fminf(fmaxf(pre, -15.f), 15.f);
        float e = __expf(2.f * xc);
        float dx = (e - 1.f) / (e + 1.f);
        float hn = hown[i] + (dx - hown[i]) * invtau_c;
        hown[i] = hn;
        if (t < SEQ - 1) {
          unsigned short hb16 = __builtin_bit_cast(unsigned short, (_Float16)hn);
          unsigned int word = ((unsigned int)hb16 << 16) | (unsigned int)(t + 1);
          unsigned int* wp = hbuf + (size_t)((t + 1) & 1) * (BATCH * HIDDEN) +
                             (size_t)(erow0 + i) * HIDDEN + ncol;
          __hip_atomic_store(wp, word, __ATOMIC_RELAXED,
                             __HIP_MEMORY_SCOPE_AGENT);
        } else {
          hfinal[(size_t)(erow0 + i) * HIDDEN + ncol] = hn;
        }
      }
    }
  }
}

// ---------------------------------------------------------------------------
// K3: out[B][256] = hfinal[B][1024] @ W_out + b_out   (fp32, tiny)
// ---------------------------------------------------------------------------
__global__ __launch_bounds__(256) void out_gemm(
    const float* __restrict__ hfinal, const float* __restrict__ Wout,
    const float* __restrict__ bout, float* __restrict__ out) {
  int b0 = blockIdx.x * 2;
  int o = threadIdx.x;
  float a0 = 0.f, a1 = 0.f;
  for (int k = 0; k < HIDDEN; ++k) {
    float wv = Wout[(size_t)k * OUTPUT + o];
    a0 += hfinal[(size_t)b0 * HIDDEN + k] * wv;
    a1 += hfinal[(size_t)(b0 + 1) * HIDDEN + k] * wv;
  }
  out[(size_t)b0 * OUTPUT + o] = a0 + bout[o];
  out[(size_t)(b0 + 1) * OUTPUT + o] = a1 + bout[o];
}

// ---------------------------------------------------------------------------
extern "C" void kernel_launch(void* const* d_in, const int* in_sizes, int n_in,
                              void* d_out, int out_size, void* d_ws,
                              size_t ws_size, hipStream_t stream) {
  const float* x     = (const float*)d_in[0];
  const float* W_in  = (const float*)d_in[1];
  const float* b_in  = (const float*)d_in[2];
  const float* W_h   = (const float*)d_in[3];
  const float* b_h   = (const float*)d_in[4];
  const float* tau   = (const float*)d_in[5];
  const float* W_out = (const float*)d_in[6];
  const float* b_out = (const float*)d_in[7];
  float* out = (float*)d_out;

  char* ws = (char*)d_ws;
  _Float16* xin = (_Float16*)ws;  ws += (size_t)BATCH * SEQ * HIDDEN * 2;  // 134MB
  _Float16* WinT = (_Float16*)ws; ws += (size_t)HIDDEN * INPUT * 2;        // 1MB
  _Float16* WhT = (_Float16*)ws;  ws += (size_t)HIDDEN * HIDDEN * 2;       // 2MB
  unsigned int* hbuf = (unsigned int*)ws;
  ws += (size_t)2 * BATCH * HIDDEN * 4;                                    // 1MB
  float* hfin = (float*)ws;       ws += (size_t)BATCH * HIDDEN * 4;        // 512KB

  // zero tags (tag 0 is never polled: t=0 skips the MFMA since h_0 = 0)
  hipMemsetAsync(hbuf, 0, (size_t)2 * BATCH * HIDDEN * 4, stream);

  transpose_f32_to_f16<<<dim3(INPUT / 32, HIDDEN / 32), 256, 0, stream>>>(
      W_in, WinT, INPUT, HIDDEN);
  transpose_f32_to_f16<<<dim3(HIDDEN / 32, HIDDEN / 32), 256, 0, stream>>>(
      W_h, WhT, HIDDEN, HIDDEN);

  xin_gemm<<<(BATCH * SEQ / 64) * (HIDDEN / 64), 256, 0, stream>>>(x, WinT, xin);

  liquid_scan<<<128, 512, 0, stream>>>(xin, WhT, b_in, b_h, tau, hbuf, hfin);

  out_gemm<<<BATCH / 2, OUTPUT, 0, stream>>>(hfin, W_out, b_out, out);
}